// Round 10
// baseline (185.266 us; speedup 1.0000x reference)
//
#include <hip/hip_runtime.h>
#include <hip/hip_bf16.h>
#include <hip/hip_fp16.h>

#define S_LEN 2048
#define E_DIM 2048
#define H_NUM 32
#define D_DIM 64

typedef __attribute__((ext_vector_type(8))) short short8;
typedef __attribute__((ext_vector_type(4))) short short4v;
typedef __attribute__((ext_vector_type(4))) float f32x4;
typedef __attribute__((ext_vector_type(4))) int i32x4;

__device__ __forceinline__ unsigned short f2h(float f) {
  return __builtin_bit_cast(unsigned short, (_Float16)f);
}

__device__ __forceinline__ float h2f(unsigned short u) {
  return (float)__builtin_bit_cast(_Float16, u);
}

__device__ __forceinline__ float fq1(float x, float invs, float scale) {
  return fminf(fmaxf(rintf(x * invs), -128.f), 127.f) * scale;
}

__device__ __forceinline__ int q8(float x, float invs) {
  return min(max((int)rintf(x * invs), -128), 127);
}

__device__ __forceinline__ void gload_lds16(const void* g, void* l) {
  __builtin_amdgcn_global_load_lds((const __attribute__((address_space(1))) void*)g,
                                   (__attribute__((address_space(3))) void*)l, 16, 0, 0);
}

__device__ __forceinline__ f32x4 mfma16h(short8 a, short8 b, f32x4 c) {
  return __builtin_amdgcn_mfma_f32_16x16x32_f16(a, b, c, 0, 0, 0);
}

__device__ __forceinline__ i32x4 mfma16i8(i32x4 a, i32x4 b, i32x4 c) {
  return __builtin_amdgcn_mfma_i32_16x16x64_i8(a, b, c, 0, 0, 0);
}

#define VMW4() asm volatile("s_waitcnt vmcnt(4)" ::: "memory")
#define VMW3() asm volatile("s_waitcnt vmcnt(3)" ::: "memory")
#define VMW2() asm volatile("s_waitcnt vmcnt(2)" ::: "memory")
#define VMW0() asm volatile("s_waitcnt vmcnt(0)" ::: "memory")
#define BARR() asm volatile("s_barrier" ::: "memory")
#define LGKM0() asm volatile("s_waitcnt lgkmcnt(0)" ::: "memory")

// ========= merged prologue: cvt + quant_w + quant_wo + sc init + RoPE table =========
// blocks [0,4096): hs cvt; [4096,10240): w_{q,k,v}; [10240,12288): w_o->i8;
// b==12288: sc init; [12289,12545): cos/sin table (65536 (s,i) pairs, f32x2).
__global__ void k_prep(const float* __restrict__ hs,
                       const float* __restrict__ w_q, const float* __restrict__ w_k,
                       const float* __restrict__ w_v, const float* __restrict__ w_o,
                       unsigned short* __restrict__ hsb, unsigned short* __restrict__ wq_all,
                       signed char* __restrict__ wo_i8, float* __restrict__ wsc,
                       unsigned* __restrict__ sc, float2* __restrict__ trig) {
  const int b = blockIdx.x;
  if (b < 4096) {
    int i = b * 256 + threadIdx.x;
    float4 v = ((const float4*)hs)[i];
    ushort4 r;
    r.x = f2h(v.x); r.y = f2h(v.y); r.z = f2h(v.z); r.w = f2h(v.w);
    ((ushort4*)hsb)[i] = r;
    return;
  }
  if (b >= 12288) {
    if (b == 12288) {
      if (threadIdx.x < 8) sc[threadIdx.x] = 0u;
      return;
    }
    // trig table: idx = (b-12289)*256 + tid -> s = idx>>5, i = idx&31
    int idx = (b - 12289) * 256 + threadIdx.x;
    int s = idx >> 5, i = idx & 31;
    float freq = exp2f(-(float)i * (13.287712379549449f / 32.f));
    float ang = (float)s * freq;
    float sn, cs;
    sincosf(ang, &sn, &cs);
    float2 t; t.x = cs; t.y = sn;
    trig[idx] = t;
    return;
  }
  __shared__ float wm[4];
  const int isWo = (b >= 10240);
  const int bb = isWo ? (b - 10240) : (b - 4096);
  const int wy = isWo ? 0 : (bb >> 11);
  const int wx = isWo ? bb : (bb & 2047);
  const float* w = isWo ? w_o : (wy == 0 ? w_q : wy == 1 ? w_k : w_v);
  const float* row = w + (size_t)wx * E_DIM;
  float4 a = ((const float4*)row)[threadIdx.x * 2];
  float4 bq = ((const float4*)row)[threadIdx.x * 2 + 1];
  float m = fmaxf(fmaxf(fmaxf(fabsf(a.x), fabsf(a.y)), fmaxf(fabsf(a.z), fabsf(a.w))),
                  fmaxf(fmaxf(fabsf(bq.x), fabsf(bq.y)), fmaxf(fabsf(bq.z), fabsf(bq.w))));
#pragma unroll
  for (int off = 32; off; off >>= 1) m = fmaxf(m, __shfl_xor(m, off));
  if ((threadIdx.x & 63) == 0) wm[threadIdx.x >> 6] = m;
  __syncthreads();
  m = fmaxf(fmaxf(wm[0], wm[1]), fmaxf(wm[2], wm[3]));
  float scale = fmaxf(m * (1.f / 127.f), 1e-8f);
  float invs = 1.f / scale;
  if (isWo) {
    unsigned lo = (unsigned)(q8(a.x, invs) & 255) | ((unsigned)(q8(a.y, invs) & 255) << 8) |
                  ((unsigned)(q8(a.z, invs) & 255) << 16) | ((unsigned)(q8(a.w, invs) & 255) << 24);
    unsigned hi = (unsigned)(q8(bq.x, invs) & 255) | ((unsigned)(q8(bq.y, invs) & 255) << 8) |
                  ((unsigned)(q8(bq.z, invs) & 255) << 16) | ((unsigned)(q8(bq.w, invs) & 255) << 24);
    uint2 pk; pk.x = lo; pk.y = hi;
    ((uint2*)(wo_i8 + (size_t)wx * E_DIM))[threadIdx.x] = pk;
    if (threadIdx.x == 0) wsc[wx] = scale;
  } else {
    unsigned short* orow = wq_all + (size_t)wy * E_DIM * E_DIM + (size_t)wx * E_DIM;
    ushort4 r0, r1;
    r0.x = f2h(fq1(a.x, invs, scale)); r0.y = f2h(fq1(a.y, invs, scale));
    r0.z = f2h(fq1(a.z, invs, scale)); r0.w = f2h(fq1(a.w, invs, scale));
    r1.x = f2h(fq1(bq.x, invs, scale)); r1.y = f2h(fq1(bq.y, invs, scale));
    r1.z = f2h(fq1(bq.z, invs, scale)); r1.w = f2h(fq1(bq.w, invs, scale));
    ((ushort4*)orow)[threadIdx.x * 2] = r0;
    ((ushort4*)orow)[threadIdx.x * 2 + 1] = r1;
  }
}

// ========= 256x256 double-buffered f16 GEMM (QKV z-fused), XCD-swizzled =========
// R7: 2 barriers per K-tile. Each half-tile: {read 12 frags + stage 2 chunks,
// lgkm, 32 MFMA, counted vmcnt(4), BARR}. Settled at 76 us / MfmaUtil 27.
__global__ __launch_bounds__(512, 2)
void k_gemm_qkv(const unsigned short* __restrict__ A, const unsigned short* __restrict__ Bt,
                unsigned short* __restrict__ C, unsigned* __restrict__ amax, float alpha_q) {
  __shared__ char lds[131072];
  const int K = 2048, NT = 32;
  // bijective XCD swizzle: 192 wgs, 192 % 8 == 0, 24 per XCD
  const int lin = blockIdx.x;
  const int swz = (lin & 7) * 24 + (lin >> 3);
  const int z = swz >> 6;
  const int t64 = swz & 63;
  const int iby = t64 >> 3;
  const int ibx = t64 & 7;
  const unsigned short* Bz = Bt + (size_t)z * E_DIM * E_DIM;
  unsigned short* Cz = C + (size_t)z * S_LEN * E_DIM;
  const float alpha = (z == 0) ? alpha_q : 1.0f;

  const int tid = threadIdx.x;
  const int wv = tid >> 6, ln = tid & 63;
  const int wm = wv >> 2, wn = wv & 3;
  const size_t bm = (size_t)ibx * 256, bn = (size_t)iby * 256;
  const int arow = ln & 15, gsl = ln >> 4;

  // LDS read byte offsets within one 64KB buffer (A: +s*16384; B: +32768+s*16384)
  int abyte[8], bbyte[4];
#pragma unroll
  for (int i = 0; i < 8; ++i) {
    int r = wm * 128 + i * 16 + arow;
    abyte[i] = r * 64 + ((gsl ^ ((r >> 1) & 3)) * 16);
  }
#pragma unroll
  for (int j = 0; j < 4; ++j) {
    int r = wn * 64 + j * 16 + arow;
    bbyte[j] = 32768 + r * 64 + ((gsl ^ ((r >> 1) & 3)) * 16);
  }

  // staging: thread tid covers rows (tid>>2) and (tid>>2)+128 of a 256x32 chunk;
  // pre-swizzled global source chunk so linear LDS dest + swizzled read agree
  const int srow = tid >> 2;
  const int scc = (tid & 3) ^ ((tid >> 3) & 3);
  const unsigned short* Asrc = A + (bm + srow) * (size_t)K + scc * 8;
  const unsigned short* Bsrc = Bz + (bn + srow) * (size_t)K + scc * 8;
  const int ldst = tid * 16;

#define STGA(T, S) do { \
    char* d_ = lds + ((T) & 1) * 65536 + (S) * 16384 + ldst; \
    const unsigned short* s_ = Asrc + (T) * 64 + (S) * 32; \
    gload_lds16(s_, d_); \
    gload_lds16(s_ + (size_t)128 * K, d_ + 8192); } while (0)
#define STGB(T, S) do { \
    char* d_ = lds + ((T) & 1) * 65536 + 32768 + (S) * 16384 + ldst; \
    const unsigned short* s_ = Bsrc + (T) * 64 + (S) * 32; \
    gload_lds16(s_, d_); \
    gload_lds16(s_ + (size_t)128 * K, d_ + 8192); } while (0)

  f32x4 acc[8][4];
#pragma unroll
  for (int i = 0; i < 8; ++i)
#pragma unroll
    for (int j = 0; j < 4; ++j) { acc[i][j][0] = 0.f; acc[i][j][1] = 0.f; acc[i][j][2] = 0.f; acc[i][j][3] = 0.f; }

  // prologue: tile 0 chunks (A-s0, B-s0, A-s1, B-s1); wait first two chunks
  STGA(0, 0); STGB(0, 0); STGA(0, 1); STGB(0, 1);
  VMW4();
  BARR();

  // One K-tile = 2 half-tiles; each: read 12 frags, stage 2 chunks, lgkm,
  // 32 MFMA (all i x j for one k-step), counted wait, barrier.
#define TILE(BUF, DS, T1, W2X, W4X) do { \
    char* bp_ = lds + (BUF); \
    short8 af_[8], bf_[4]; \
    /* ---- half 1: k-step 0, all 32 MFMA; stage A/B(t+1) s0 ---- */ \
    _Pragma("unroll") for (int i = 0; i < 8; ++i) af_[i] = *(const short8*)(bp_ + abyte[i]); \
    _Pragma("unroll") for (int j = 0; j < 4; ++j) bf_[j] = *(const short8*)(bp_ + bbyte[j]); \
    if (DS) { STGA(T1, 0); STGB(T1, 0); } \
    LGKM0(); \
    __builtin_amdgcn_s_setprio(1); \
    _Pragma("unroll") for (int i = 0; i < 8; ++i) \
      _Pragma("unroll") for (int j = 0; j < 4; ++j) acc[i][j] = mfma16h(af_[i], bf_[j], acc[i][j]); \
    __builtin_amdgcn_s_setprio(0); \
    W2X; \
    BARR(); \
    /* ---- half 2: k-step 1, all 32 MFMA; stage A/B(t+1) s1 ---- */ \
    _Pragma("unroll") for (int i = 0; i < 8; ++i) af_[i] = *(const short8*)(bp_ + 16384 + abyte[i]); \
    _Pragma("unroll") for (int j = 0; j < 4; ++j) bf_[j] = *(const short8*)(bp_ + 16384 + bbyte[j]); \
    if (DS) { STGA(T1, 1); STGB(T1, 1); } \
    LGKM0(); \
    __builtin_amdgcn_s_setprio(1); \
    _Pragma("unroll") for (int i = 0; i < 8; ++i) \
      _Pragma("unroll") for (int j = 0; j < 4; ++j) acc[i][j] = mfma16h(af_[i], bf_[j], acc[i][j]); \
    __builtin_amdgcn_s_setprio(0); \
    W4X; \
    BARR(); \
  } while (0)

#pragma unroll 1
  for (int t = 0; t < NT - 2; t += 2) {
    TILE(0, 1, t + 1, VMW4(), VMW4());
    TILE(65536, 1, t + 2, VMW4(), VMW4());
  }
  TILE(0, 1, NT - 1, VMW4(), VMW4());
  TILE(65536, 0, 0, VMW0(), (void)0);
#undef TILE
#undef STGA
#undef STGB

  float amx = 0.f;
#pragma unroll
  for (int i = 0; i < 8; ++i) {
    size_t rowb = bm + wm * 128 + i * 16 + gsl * 4;
#pragma unroll
    for (int j = 0; j < 4; ++j) {
      size_t col = bn + wn * 64 + j * 16 + arow;
#pragma unroll
      for (int r = 0; r < 4; ++r) {
        float v = acc[i][j][r] * alpha;
        Cz[(rowb + r) * E_DIM + col] = f2h(v);
        amx = fmaxf(amx, fabsf(v));
      }
    }
  }
#pragma unroll
  for (int off = 32; off; off >>= 1) amx = fmaxf(amx, __shfl_xor(amx, off));
  if (ln == 0) atomicMax(amax + z, __float_as_uint(amx));
}

// ========= o-proj: 128x64 tri-buffered INT8 GEMM, XCD-swizzled =========
__global__ __launch_bounds__(256, 4)
void k_gemm_o(const signed char* __restrict__ A, const signed char* __restrict__ Bt,
              float* __restrict__ C, const unsigned* __restrict__ sc,
              const float* __restrict__ wsc) {
  __shared__ char lds[36864];
  const int K = 2048, NT = 32;
  const float sa = fmaxf(__uint_as_float(sc[3]) * (1.f / 127.f), 1e-8f);
  const int lin = blockIdx.y * 16 + blockIdx.x;
  const int swz = (lin & 7) * 64 + (lin >> 3);
  const int iby = swz >> 4;
  const int ibx = swz & 15;

  const int tid = threadIdx.x;
  const int wv = tid >> 6, ln = tid & 63;
  const int wm = wv >> 1, wn = wv & 1;
  const size_t bm = (size_t)ibx * 128, bn = (size_t)iby * 64;
  const int arow = ln & 15, gsl = ln >> 4;

  int abyte[4], bbyte[2];
#pragma unroll
  for (int i = 0; i < 4; ++i) {
    int ra = wm * 64 + i * 16 + arow;
    abyte[i] = ra * 64 + ((gsl ^ ((ra >> 1) & 3)) * 16);
  }
#pragma unroll
  for (int j = 0; j < 2; ++j) {
    int rb = wn * 32 + j * 16 + arow;
    bbyte[j] = rb * 64 + ((gsl ^ ((rb >> 1) & 3)) * 16);
  }

  const int srow = tid >> 2;
  const int sl = (tid & 3) ^ ((srow >> 1) & 3);
  const signed char* Ast = A + (bm + srow) * (size_t)K + sl * 16;
  const signed char* Bst = Bt + (bn + srow) * (size_t)K + sl * 16;

#define STG(T, dst) do { if ((T) < NT) { \
    size_t go = (size_t)(T) * 64; \
    gload_lds16(Ast + go, (dst) + wv * 1024); \
    gload_lds16(Ast + go + (size_t)64 * K, (dst) + 4096 + wv * 1024); \
    gload_lds16(Bst + go, (dst) + 8192 + wv * 1024); } } while (0)

  i32x4 acc[4][2];
#pragma unroll
  for (int i = 0; i < 4; ++i)
#pragma unroll
    for (int j = 0; j < 2; ++j) { acc[i][j][0] = 0; acc[i][j][1] = 0; acc[i][j][2] = 0; acc[i][j][3] = 0; }

  char* b0 = lds;
  char* b1 = lds + 12288;
  char* b2 = lds + 24576;

  STG(0, b0); STG(1, b1);
  VMW3();
  BARR();

#define ITER(T, bufR, bufS) do { \
    i32x4 af[4], bf[2]; \
    _Pragma("unroll") \
    for (int i = 0; i < 4; ++i) af[i] = *(const i32x4*)((bufR) + abyte[i]); \
    _Pragma("unroll") \
    for (int j = 0; j < 2; ++j) bf[j] = *(const i32x4*)((bufR) + 8192 + bbyte[j]); \
    STG((T) + 2, bufS); \
    __builtin_amdgcn_s_setprio(1); \
    _Pragma("unroll") \
    for (int i = 0; i < 4; ++i) \
      _Pragma("unroll") \
      for (int j = 0; j < 2; ++j) acc[i][j] = mfma16i8(af[i], bf[j], acc[i][j]); \
    __builtin_amdgcn_s_setprio(0); \
    if ((T) == NT - 2) { VMW0(); } else if ((T) < NT - 2) { VMW3(); } \
    BARR(); } while (0)

#pragma unroll 1
  for (int t = 0; t + 2 < NT; t += 3) {
    ITER(t, b0, b2);
    ITER(t + 1, b1, b0);
    ITER(t + 2, b2, b1);
  }
  ITER(NT - 2, b0, b2);
  ITER(NT - 1, b1, b0);
#undef ITER
#undef STG

#pragma unroll
  for (int i = 0; i < 4; ++i) {
    size_t rowb = bm + wm * 64 + i * 16 + gsl * 4;
#pragma unroll
    for (int j = 0; j < 2; ++j) {
      size_t col = bn + wn * 32 + j * 16 + arow;
      float s = sa * wsc[col];
#pragma unroll
      for (int r = 0; r < 4; ++r)
        C[(rowb + r) * E_DIM + col] = (float)acc[i][j][r] * s;
    }
  }
}

// ========= merged RoPE(q,k, table-driven, VECTORIZED) + V-transpose (f16) =========
// q/k path (z<2): 64 blocks x 32 rows. Each thread owns 8 contiguous dims
// (one short8 load + one short8 store); rotate-half partner (i <-> i+32) comes
// from lane tid^4 via 4x shfl_xor (lanes j and j^4 hold the two halves of the
// same row). 8x fewer memory instructions than the scalar-2B version.
__global__ void k_rvt(const unsigned short* __restrict__ qkv,
                      unsigned short* __restrict__ Qh, unsigned short* __restrict__ Kh,
                      unsigned short* __restrict__ Vt, const unsigned* __restrict__ sc,
                      const float2* __restrict__ trig) {
  __shared__ float tb[64][65];
  const int z = blockIdx.z;
  if (z < 2) {
    const unsigned short* x = qkv + (z ? 4194304 : 0);
    unsigned short* out = z ? Kh : Qh;
    float scale = fmaxf(__uint_as_float(sc[z]) * (1.f / 127.f), 1e-8f);
    float invs = 1.f / scale;
    const int h = blockIdx.y;
    const int tid = threadIdx.x;
    const int s = blockIdx.x * 32 + (tid >> 3);
    const int j = tid & 7;
    // my 8 raw values: dims [j*8, j*8+8)
    short8 v = *(const short8*)(x + (size_t)s * E_DIM + h * 64 + j * 8);
    // partner (dims +-32): lane tid^4 (same row: tid>>3 unchanged)
    int pi[4];
    {
      const int* vi = (const int*)&v;
#pragma unroll
      for (int w = 0; w < 4; ++w) pi[w] = __shfl_xor(vi[w], 4);
    }
    short8 p = *(const short8*)pi;
    // out[i]    = q0*cos_i - q1*sin_i   (j<4: mine=q0, partner=q1)
    // out[i+32] = q1*cos_i + q0*sin_i   (j>=4: mine=q1, partner=q0)
    const float sgn = (j < 4) ? -1.f : 1.f;
    const float2* tp = trig + s * 32 + (j & 3) * 8;
    short8 ro;
#pragma unroll
    for (int e = 0; e < 8; ++e) {
      float me = fq1(h2f((unsigned short)v[e]), invs, scale);
      float pe = fq1(h2f((unsigned short)p[e]), invs, scale);
      float2 t = tp[e];
      ro[e] = (short)f2h(me * t.x + sgn * (pe * t.y));
    }
    *(short8*)(out + (size_t)h * S_LEN * D_DIM + (size_t)s * D_DIM + j * 8) = ro;
    return;
  }
  if (blockIdx.x >= 32) return;
  const unsigned short* v = qkv + 2 * 4194304;
  float scale = fmaxf(__uint_as_float(sc[2]) * (1.f / 127.f), 1e-8f);
  float invs = 1.f / scale;
  int s0 = blockIdx.x * 64, h = blockIdx.y;
#pragma unroll
  for (int l = 0; l < 16; ++l) {
    int idx = threadIdx.x + l * 256;
    int r = idx >> 6, c = idx & 63;
    float x = h2f(v[(size_t)(s0 + r) * E_DIM + h * 64 + c]);
    tb[r][c] = fq1(x, invs, scale);
  }
  __syncthreads();
#pragma unroll
  for (int l = 0; l < 16; ++l) {
    int idx = threadIdx.x + l * 256;
    int d = idx >> 6, s = idx & 63;
    Vt[(size_t)h * D_DIM * S_LEN + (size_t)d * S_LEN + s0 + s] = f2h(tb[s][d]);
  }
}

// -------- causal flash attention: 512 thr / 8 waves, 128 q-rows, 1 group/wave ----
// R9: keep R8's K/V amortization (128 rows share each staged tile) but give each
// wave ONE 16-row group (wave wv owns rows qc*128 + wv*16). Removes the 2-group
// register doubling -> fits the 128-VGPR cap -> launch_bounds(512,4) -> 2 blocks/CU
// = 16 waves/CU (2x R8's 8): the per-iter dependency chain (QK->softmax->PV) is
// latency-bound and needs TLP to hide. LDS 48KB (2x8K K + 2x8K V + 16K P).
// Causality: at the last k-tile waves 0-3 are fully masked -> skip compute only
// (skipped region has wave-local barriers only; block barriers stay uniform).
__global__ __launch_bounds__(512, 4)
void k_attn(const unsigned short* __restrict__ Qh, const unsigned short* __restrict__ Kh,
            const unsigned short* __restrict__ Vt, unsigned short* __restrict__ att,
            unsigned* __restrict__ amax) {
  __shared__ char Kbuf[2 * 8192];
  __shared__ char Vbuf[2 * 8192];
  __shared__ __align__(16) char Pb[16384];
  const int L = blockIdx.x;
  const int h = L & 31;
  const int g5 = L >> 5;                              // [0,16)
  const int qc = (g5 < 8) ? (15 - g5) : (g5 - 8);     // balanced pairing
  const int nt = 2 * qc + 2;
  const int tid = threadIdx.x;
  const int wv = tid >> 6, ln = tid & 63;
  const int arow = ln & 15, gsl = ln >> 4;
  const unsigned short* Qb = Qh + (size_t)h * S_LEN * D_DIM;
  const unsigned short* Kb = Kh + (size_t)h * S_LEN * D_DIM;
  const unsigned short* Vb = Vt + (size_t)h * D_DIM * S_LEN;
  const int qr = qc * 128 + wv * 16;                  // this wave's 16 q-rows

  // staging: 512 threads x 16B = one 8KB (64x128B) tile per call
  const int srow = tid >> 3, sch = (tid & 7) ^ (srow & 7);

#define STAGEK(T, B) do { char* kd = Kbuf + (B) * 8192; const int tb_ = (T) * 64; \
    gload_lds16(Kb + (size_t)(tb_ + srow) * D_DIM + sch * 8, kd + wv * 1024); } while (0)
#define STAGEV(T, B) do { char* vd = Vbuf + (B) * 8192; const int tb_ = (T) * 64; \
    gload_lds16(Vb + (size_t)srow * S_LEN + tb_ + sch * 8, vd + wv * 1024); } while (0)

  short8 qa0 = *(const short8*)(Qb + (size_t)(qr + arow) * D_DIM + gsl * 8);
  short8 qa1 = *(const short8*)(Qb + (size_t)(qr + arow) * D_DIM + 32 + gsl * 8);

  f32x4 o[4];
  float mrow = -INFINITY, lrow = 0.f;
#pragma unroll
  for (int d = 0; d < 4; ++d) { o[d][0] = 0.f; o[d][1] = 0.f; o[d][2] = 0.f; o[d][3] = 0.f; }

  STAGEK(0, 0); STAGEV(0, 0);
  STAGEK(1, 1); STAGEV(1, 1);
  VMW2();
  BARR();

  char* Pw = Pb + wv * 2048 + arow * 128;
  const int arw7 = arow & 7;

#pragma unroll 1
  for (int t = 0; t < nt; ++t) {
    if (t >= 1 && t + 1 < nt) { STAGEK(t + 1, (t + 1) & 1); STAGEV(t + 1, (t + 1) & 1); }

    // waves 0-3 (rows qc*128 .. +64) are fully masked at the final tile
    if (!(t == nt - 1 && wv < 4)) {
      char* kb = Kbuf + (t & 1) * 8192;
      char* vb = Vbuf + (t & 1) * 8192;

      short8 kf[4][2];
#pragma unroll
      for (int kvb = 0; kvb < 4; ++kvb) {
        int row = kvb * 16 + arow;
        int sw = (row & 7) << 4;
        kf[kvb][0] = *(const short8*)(kb + row * 128 + ((gsl * 16) ^ sw));
        kf[kvb][1] = *(const short8*)(kb + row * 128 + ((64 + gsl * 16) ^ sw));
      }
      f32x4 s4[4];
#pragma unroll
      for (int kvb = 0; kvb < 4; ++kvb) {
        s4[kvb][0] = 0.f; s4[kvb][1] = 0.f; s4[kvb][2] = 0.f; s4[kvb][3] = 0.f;
      }
#pragma unroll
      for (int kvb = 0; kvb < 4; ++kvb) {
        s4[kvb] = mfma16h(kf[kvb][0], qa0, s4[kvb]);
        s4[kvb] = mfma16h(kf[kvb][1], qa1, s4[kvb]);
      }

      const int t0 = t * 64;
      const int qrow = qr + arow;
      if (t0 + 63 > qrow) {
#pragma unroll
        for (int kvb = 0; kvb < 4; ++kvb) {
          int colb = t0 + kvb * 16 + gsl * 4;
#pragma unroll
          for (int r = 0; r < 4; ++r)
            if (colb + r > qrow) s4[kvb][r] = -INFINITY;
        }
      }

      float smax = s4[0][0];
#pragma unroll
      for (int kvb = 0; kvb < 4; ++kvb)
#pragma unroll
        for (int r = 0; r < 4; ++r) smax = fmaxf(smax, s4[kvb][r]);
      smax = fmaxf(smax, __shfl_xor(smax, 16));
      smax = fmaxf(smax, __shfl_xor(smax, 32));

      float mn = fmaxf(mrow, smax);
      float corr = __expf(mrow - mn);
      mrow = mn;

      float rs = 0.f;
      float p4[4][4];
#pragma unroll
      for (int kvb = 0; kvb < 4; ++kvb)
#pragma unroll
        for (int r = 0; r < 4; ++r) {
          p4[kvb][r] = __expf(s4[kvb][r] - mn);
          rs += p4[kvb][r];
        }
      rs += __shfl_xor(rs, 16);
      rs += __shfl_xor(rs, 32);
      lrow = lrow * corr + rs;

      float corr_r[4];
#pragma unroll
      for (int r = 0; r < 4; ++r) corr_r[r] = __shfl(corr, gsl * 4 + r);
#pragma unroll
      for (int d = 0; d < 4; ++d)
#pragma unroll
        for (int r = 0; r < 4; ++r) o[d][r] *= corr_r[r];

      __builtin_amdgcn_wave_barrier();
#pragma unroll
      for (int kvb = 0; kvb < 4; ++kvb) {
        short4v pw;
        pw[0] = (short)f2h(p4[kvb][0]);
        pw[1] = (short)f2h(p4[kvb][1]);
        pw[2] = (short)f2h(p4[kvb][2]);
        pw[3] = (short)f2h(p4[kvb][3]);
        const int u = kvb * 2 + (gsl >> 1);
        *(short4v*)(Pw + ((u ^ arw7) << 4) + ((gsl & 1) << 3)) = pw;
      }
      __builtin_amdgcn_wave_barrier();
      short8 pa0 = *(const short8*)(Pw + ((gsl ^ arw7) << 4));
      short8 pa1 = *(const short8*)(Pw + (((4 + gsl) ^ arw7) << 4));
      __builtin_amdgcn_wave_barrier();

      short8 vf[4][2];
#pragma unroll
      for (int d = 0; d < 4; ++d) {
        int row = d * 16 + arow;
        int sw = (row & 7) << 4;
        vf[d][0] = *(const short8*)(vb + row * 128 + ((gsl * 16) ^ sw));
        vf[d][1] = *(const short8*)(vb + row * 128 + ((64 + gsl * 16) ^ sw));
      }
#pragma unroll
      for (int d = 0; d < 4; ++d) {
        o[d] = mfma16h(pa0, vf[d][0], o[d]);
        o[d] = mfma16h(pa1, vf[d][1], o[d]);
      }
    }

    VMW0();
    BARR();
  }
#undef STAGEK
#undef STAGEV

  float amx = 0.f;
  float invl = 1.f / lrow;
  float invl_r[4];
#pragma unroll
  for (int r = 0; r < 4; ++r) invl_r[r] = __shfl(invl, gsl * 4 + r);
#pragma unroll
  for (int r = 0; r < 4; ++r) {
    size_t row = (size_t)(qr + gsl * 4 + r);
#pragma unroll
    for (int d = 0; d < 4; ++d) {
      float v = o[d][r] * invl_r[r];
      att[row * E_DIM + h * 64 + d * 16 + arow] = f2h(v);
      amx = fmaxf(amx, fabsf(v));
    }
  }

#pragma unroll
  for (int off = 32; off; off >>= 1) amx = fmaxf(amx, __shfl_xor(amx, off));
  if (ln == 0) atomicMax(amax + 3, __float_as_uint(amx));
}

// ---------------- act fake-quant f16 -> packed int8 (8 elems/thread) ----------------
__global__ void k_quant_act_i8(const unsigned short* __restrict__ in, uint2* __restrict__ out,
                               const unsigned* __restrict__ sc, int idx) {
  float scale = fmaxf(__uint_as_float(sc[idx]) * (1.f / 127.f), 1e-8f);
  float invs = 1.f / scale;
  int i = blockIdx.x * blockDim.x + threadIdx.x;
  short8 v = ((const short8*)in)[i];
  unsigned lo = 0, hi = 0;
#pragma unroll
  for (int e = 0; e < 4; ++e)
    lo |= (unsigned)(q8(h2f((unsigned short)v[e]), invs) & 255) << (8 * e);
#pragma unroll
  for (int e = 0; e < 4; ++e)
    hi |= (unsigned)(q8(h2f((unsigned short)v[4 + e]), invs) & 255) << (8 * e);
  uint2 pk; pk.x = lo; pk.y = hi;
  out[i] = pk;
}

extern "C" void kernel_launch(void* const* d_in, const int* in_sizes, int n_in,
                              void* d_out, int out_size, void* d_ws, size_t ws_size,
                              hipStream_t stream) {
  const float* hs = (const float*)d_in[0];
  const float* w_q = (const float*)d_in[1];
  const float* w_k = (const float*)d_in[2];
  const float* w_v = (const float*)d_in[3];
  const float* w_o = (const float*)d_in[4];

  char* ws = (char*)d_ws;
  unsigned short* wq_all = (unsigned short*)(ws);                 // 3 x E*E f16 (q,k,v)
  signed char* wo_i8 = (signed char*)(ws + 25165824);             // E*E i8
  float* wsc = (float*)(ws + 29360128);                           // 2048 f32
  float2* trig = (float2*)(ws + 30408704);                        // 65536 float2 (512KB)
  unsigned short* hsb = (unsigned short*)(ws + 33554432);         // S*E f16
  unsigned short* qkv16 = (unsigned short*)(ws + 41943040);       // 3 x S*E f16
  unsigned short* att = qkv16;                                    // alias q slab (f16)
  signed char* aq_i8 = (signed char*)(ws + 67108864);             // S*E i8
  unsigned short* Qh = (unsigned short*)(ws + 92274688);          // [H][S][D] f16
  unsigned short* Kh = (unsigned short*)(ws + 100663296);
  unsigned short* Vt = (unsigned short*)(ws + 109051904);         // [H][D][S] f16
  unsigned* sc = (unsigned*)(ws + 117440512);                     // absmax scalars

  k_prep<<<12545, 256, 0, stream>>>(hs, w_q, w_k, w_v, w_o, hsb, wq_all, wo_i8, wsc, sc, trig);
  k_gemm_qkv<<<dim3(192), 512, 0, stream>>>(hsb, wq_all, qkv16, sc, 0.125f);
  k_rvt<<<dim3(64, 32, 3), 256, 0, stream>>>(qkv16, Qh, Kh, Vt, sc, trig);
  k_attn<<<512, 512, 0, stream>>>(Qh, Kh, Vt, att, sc);
  k_quant_act_i8<<<2048, 256, 0, stream>>>(att, (uint2*)aq_i8, sc, 3);
  k_gemm_o<<<dim3(16, 32), 256, 0, stream>>>(aq_i8, wo_i8, (float*)d_out, sc, wsc);
}

// Round 11
// 175.343 us; speedup vs baseline: 1.0566x; 1.0566x over previous
//
#include <hip/hip_runtime.h>
#include <hip/hip_bf16.h>
#include <hip/hip_fp16.h>

#define S_LEN 2048
#define E_DIM 2048
#define H_NUM 32
#define D_DIM 64

typedef __attribute__((ext_vector_type(8))) short short8;
typedef __attribute__((ext_vector_type(4))) short short4v;
typedef __attribute__((ext_vector_type(4))) float f32x4;
typedef __attribute__((ext_vector_type(4))) int i32x4;

__device__ __forceinline__ unsigned short f2h(float f) {
  return __builtin_bit_cast(unsigned short, (_Float16)f);
}

__device__ __forceinline__ float h2f(unsigned short u) {
  return (float)__builtin_bit_cast(_Float16, u);
}

__device__ __forceinline__ float fq1(float x, float invs, float scale) {
  return fminf(fmaxf(rintf(x * invs), -128.f), 127.f) * scale;
}

__device__ __forceinline__ int q8(float x, float invs) {
  return min(max((int)rintf(x * invs), -128), 127);
}

__device__ __forceinline__ void gload_lds16(const void* g, void* l) {
  __builtin_amdgcn_global_load_lds((const __attribute__((address_space(1))) void*)g,
                                   (__attribute__((address_space(3))) void*)l, 16, 0, 0);
}

__device__ __forceinline__ f32x4 mfma16h(short8 a, short8 b, f32x4 c) {
  return __builtin_amdgcn_mfma_f32_16x16x32_f16(a, b, c, 0, 0, 0);
}

__device__ __forceinline__ i32x4 mfma16i8(i32x4 a, i32x4 b, i32x4 c) {
  return __builtin_amdgcn_mfma_i32_16x16x64_i8(a, b, c, 0, 0, 0);
}

#define VMW4() asm volatile("s_waitcnt vmcnt(4)" ::: "memory")
#define VMW3() asm volatile("s_waitcnt vmcnt(3)" ::: "memory")
#define VMW0() asm volatile("s_waitcnt vmcnt(0)" ::: "memory")
#define BARR() asm volatile("s_barrier" ::: "memory")
#define LGKM0() asm volatile("s_waitcnt lgkmcnt(0)" ::: "memory")

// ========= merged prologue: cvt + quant_w + quant_wo + sc init + RoPE table =========
// blocks [0,4096): hs cvt; [4096,10240): w_{q,k,v}; [10240,12288): w_o->i8;
// b==12288: sc init; [12289,12545): cos/sin table (65536 (s,i) pairs, f32x2).
__global__ void k_prep(const float* __restrict__ hs,
                       const float* __restrict__ w_q, const float* __restrict__ w_k,
                       const float* __restrict__ w_v, const float* __restrict__ w_o,
                       unsigned short* __restrict__ hsb, unsigned short* __restrict__ wq_all,
                       signed char* __restrict__ wo_i8, float* __restrict__ wsc,
                       unsigned* __restrict__ sc, float2* __restrict__ trig) {
  const int b = blockIdx.x;
  if (b < 4096) {
    int i = b * 256 + threadIdx.x;
    float4 v = ((const float4*)hs)[i];
    ushort4 r;
    r.x = f2h(v.x); r.y = f2h(v.y); r.z = f2h(v.z); r.w = f2h(v.w);
    ((ushort4*)hsb)[i] = r;
    return;
  }
  if (b >= 12288) {
    if (b == 12288) {
      if (threadIdx.x < 8) sc[threadIdx.x] = 0u;
      return;
    }
    // trig table: idx = (b-12289)*256 + tid -> s = idx>>5, i = idx&31
    int idx = (b - 12289) * 256 + threadIdx.x;
    int s = idx >> 5, i = idx & 31;
    float freq = exp2f(-(float)i * (13.287712379549449f / 32.f));
    float ang = (float)s * freq;
    float sn, cs;
    sincosf(ang, &sn, &cs);
    float2 t; t.x = cs; t.y = sn;
    trig[idx] = t;
    return;
  }
  __shared__ float wm[4];
  const int isWo = (b >= 10240);
  const int bb = isWo ? (b - 10240) : (b - 4096);
  const int wy = isWo ? 0 : (bb >> 11);
  const int wx = isWo ? bb : (bb & 2047);
  const float* w = isWo ? w_o : (wy == 0 ? w_q : wy == 1 ? w_k : w_v);
  const float* row = w + (size_t)wx * E_DIM;
  float4 a = ((const float4*)row)[threadIdx.x * 2];
  float4 bq = ((const float4*)row)[threadIdx.x * 2 + 1];
  float m = fmaxf(fmaxf(fmaxf(fabsf(a.x), fabsf(a.y)), fmaxf(fabsf(a.z), fabsf(a.w))),
                  fmaxf(fmaxf(fabsf(bq.x), fabsf(bq.y)), fmaxf(fabsf(bq.z), fabsf(bq.w))));
#pragma unroll
  for (int off = 32; off; off >>= 1) m = fmaxf(m, __shfl_xor(m, off));
  if ((threadIdx.x & 63) == 0) wm[threadIdx.x >> 6] = m;
  __syncthreads();
  m = fmaxf(fmaxf(wm[0], wm[1]), fmaxf(wm[2], wm[3]));
  float scale = fmaxf(m * (1.f / 127.f), 1e-8f);
  float invs = 1.f / scale;
  if (isWo) {
    unsigned lo = (unsigned)(q8(a.x, invs) & 255) | ((unsigned)(q8(a.y, invs) & 255) << 8) |
                  ((unsigned)(q8(a.z, invs) & 255) << 16) | ((unsigned)(q8(a.w, invs) & 255) << 24);
    unsigned hi = (unsigned)(q8(bq.x, invs) & 255) | ((unsigned)(q8(bq.y, invs) & 255) << 8) |
                  ((unsigned)(q8(bq.z, invs) & 255) << 16) | ((unsigned)(q8(bq.w, invs) & 255) << 24);
    uint2 pk; pk.x = lo; pk.y = hi;
    ((uint2*)(wo_i8 + (size_t)wx * E_DIM))[threadIdx.x] = pk;
    if (threadIdx.x == 0) wsc[wx] = scale;
  } else {
    unsigned short* orow = wq_all + (size_t)wy * E_DIM * E_DIM + (size_t)wx * E_DIM;
    ushort4 r0, r1;
    r0.x = f2h(fq1(a.x, invs, scale)); r0.y = f2h(fq1(a.y, invs, scale));
    r0.z = f2h(fq1(a.z, invs, scale)); r0.w = f2h(fq1(a.w, invs, scale));
    r1.x = f2h(fq1(bq.x, invs, scale)); r1.y = f2h(fq1(bq.y, invs, scale));
    r1.z = f2h(fq1(bq.z, invs, scale)); r1.w = f2h(fq1(bq.w, invs, scale));
    ((ushort4*)orow)[threadIdx.x * 2] = r0;
    ((ushort4*)orow)[threadIdx.x * 2 + 1] = r1;
  }
}

// ========= 256x256 double-buffered f16 GEMM (QKV z-fused), XCD-swizzled =========
// R7: 2 barriers per K-tile. Each half-tile: {read 12 frags + stage 2 chunks,
// lgkm, 32 MFMA, counted vmcnt(4), BARR}. Settled at 76 us / MfmaUtil 27.
__global__ __launch_bounds__(512, 2)
void k_gemm_qkv(const unsigned short* __restrict__ A, const unsigned short* __restrict__ Bt,
                unsigned short* __restrict__ C, unsigned* __restrict__ amax, float alpha_q) {
  __shared__ char lds[131072];
  const int K = 2048, NT = 32;
  // bijective XCD swizzle: 192 wgs, 192 % 8 == 0, 24 per XCD
  const int lin = blockIdx.x;
  const int swz = (lin & 7) * 24 + (lin >> 3);
  const int z = swz >> 6;
  const int t64 = swz & 63;
  const int iby = t64 >> 3;
  const int ibx = t64 & 7;
  const unsigned short* Bz = Bt + (size_t)z * E_DIM * E_DIM;
  unsigned short* Cz = C + (size_t)z * S_LEN * E_DIM;
  const float alpha = (z == 0) ? alpha_q : 1.0f;

  const int tid = threadIdx.x;
  const int wv = tid >> 6, ln = tid & 63;
  const int wm = wv >> 2, wn = wv & 3;
  const size_t bm = (size_t)ibx * 256, bn = (size_t)iby * 256;
  const int arow = ln & 15, gsl = ln >> 4;

  // LDS read byte offsets within one 64KB buffer (A: +s*16384; B: +32768+s*16384)
  int abyte[8], bbyte[4];
#pragma unroll
  for (int i = 0; i < 8; ++i) {
    int r = wm * 128 + i * 16 + arow;
    abyte[i] = r * 64 + ((gsl ^ ((r >> 1) & 3)) * 16);
  }
#pragma unroll
  for (int j = 0; j < 4; ++j) {
    int r = wn * 64 + j * 16 + arow;
    bbyte[j] = 32768 + r * 64 + ((gsl ^ ((r >> 1) & 3)) * 16);
  }

  // staging: thread tid covers rows (tid>>2) and (tid>>2)+128 of a 256x32 chunk;
  // pre-swizzled global source chunk so linear LDS dest + swizzled read agree
  const int srow = tid >> 2;
  const int scc = (tid & 3) ^ ((tid >> 3) & 3);
  const unsigned short* Asrc = A + (bm + srow) * (size_t)K + scc * 8;
  const unsigned short* Bsrc = Bz + (bn + srow) * (size_t)K + scc * 8;
  const int ldst = tid * 16;

#define STGA(T, S) do { \
    char* d_ = lds + ((T) & 1) * 65536 + (S) * 16384 + ldst; \
    const unsigned short* s_ = Asrc + (T) * 64 + (S) * 32; \
    gload_lds16(s_, d_); \
    gload_lds16(s_ + (size_t)128 * K, d_ + 8192); } while (0)
#define STGB(T, S) do { \
    char* d_ = lds + ((T) & 1) * 65536 + 32768 + (S) * 16384 + ldst; \
    const unsigned short* s_ = Bsrc + (T) * 64 + (S) * 32; \
    gload_lds16(s_, d_); \
    gload_lds16(s_ + (size_t)128 * K, d_ + 8192); } while (0)

  f32x4 acc[8][4];
#pragma unroll
  for (int i = 0; i < 8; ++i)
#pragma unroll
    for (int j = 0; j < 4; ++j) { acc[i][j][0] = 0.f; acc[i][j][1] = 0.f; acc[i][j][2] = 0.f; acc[i][j][3] = 0.f; }

  // prologue: tile 0 chunks (A-s0, B-s0, A-s1, B-s1); wait first two chunks
  STGA(0, 0); STGB(0, 0); STGA(0, 1); STGB(0, 1);
  VMW4();
  BARR();

  // One K-tile = 2 half-tiles; each: read 12 frags, stage 2 chunks, lgkm,
  // 32 MFMA (all i x j for one k-step), counted wait, barrier.
#define TILE(BUF, DS, T1, W2X, W4X) do { \
    char* bp_ = lds + (BUF); \
    short8 af_[8], bf_[4]; \
    /* ---- half 1: k-step 0, all 32 MFMA; stage A/B(t+1) s0 ---- */ \
    _Pragma("unroll") for (int i = 0; i < 8; ++i) af_[i] = *(const short8*)(bp_ + abyte[i]); \
    _Pragma("unroll") for (int j = 0; j < 4; ++j) bf_[j] = *(const short8*)(bp_ + bbyte[j]); \
    if (DS) { STGA(T1, 0); STGB(T1, 0); } \
    LGKM0(); \
    __builtin_amdgcn_s_setprio(1); \
    _Pragma("unroll") for (int i = 0; i < 8; ++i) \
      _Pragma("unroll") for (int j = 0; j < 4; ++j) acc[i][j] = mfma16h(af_[i], bf_[j], acc[i][j]); \
    __builtin_amdgcn_s_setprio(0); \
    W2X; \
    BARR(); \
    /* ---- half 2: k-step 1, all 32 MFMA; stage A/B(t+1) s1 ---- */ \
    _Pragma("unroll") for (int i = 0; i < 8; ++i) af_[i] = *(const short8*)(bp_ + 16384 + abyte[i]); \
    _Pragma("unroll") for (int j = 0; j < 4; ++j) bf_[j] = *(const short8*)(bp_ + 16384 + bbyte[j]); \
    if (DS) { STGA(T1, 1); STGB(T1, 1); } \
    LGKM0(); \
    __builtin_amdgcn_s_setprio(1); \
    _Pragma("unroll") for (int i = 0; i < 8; ++i) \
      _Pragma("unroll") for (int j = 0; j < 4; ++j) acc[i][j] = mfma16h(af_[i], bf_[j], acc[i][j]); \
    __builtin_amdgcn_s_setprio(0); \
    W4X; \
    BARR(); \
  } while (0)

#pragma unroll 1
  for (int t = 0; t < NT - 2; t += 2) {
    TILE(0, 1, t + 1, VMW4(), VMW4());
    TILE(65536, 1, t + 2, VMW4(), VMW4());
  }
  TILE(0, 1, NT - 1, VMW4(), VMW4());
  TILE(65536, 0, 0, VMW0(), (void)0);
#undef TILE
#undef STGA
#undef STGB

  float amx = 0.f;
#pragma unroll
  for (int i = 0; i < 8; ++i) {
    size_t rowb = bm + wm * 128 + i * 16 + gsl * 4;
#pragma unroll
    for (int j = 0; j < 4; ++j) {
      size_t col = bn + wn * 64 + j * 16 + arow;
#pragma unroll
      for (int r = 0; r < 4; ++r) {
        float v = acc[i][j][r] * alpha;
        Cz[(rowb + r) * E_DIM + col] = f2h(v);
        amx = fmaxf(amx, fabsf(v));
      }
    }
  }
#pragma unroll
  for (int off = 32; off; off >>= 1) amx = fmaxf(amx, __shfl_xor(amx, off));
  if (ln == 0) atomicMax(amax + z, __float_as_uint(amx));
}

// ========= o-proj: 128x64 tri-buffered INT8 GEMM, XCD-swizzled =========
__global__ __launch_bounds__(256, 4)
void k_gemm_o(const signed char* __restrict__ A, const signed char* __restrict__ Bt,
              float* __restrict__ C, const unsigned* __restrict__ sc,
              const float* __restrict__ wsc) {
  __shared__ char lds[36864];
  const int K = 2048, NT = 32;
  const float sa = fmaxf(__uint_as_float(sc[3]) * (1.f / 127.f), 1e-8f);
  const int lin = blockIdx.y * 16 + blockIdx.x;
  const int swz = (lin & 7) * 64 + (lin >> 3);
  const int iby = swz >> 4;
  const int ibx = swz & 15;

  const int tid = threadIdx.x;
  const int wv = tid >> 6, ln = tid & 63;
  const int wm = wv >> 1, wn = wv & 1;
  const size_t bm = (size_t)ibx * 128, bn = (size_t)iby * 64;
  const int arow = ln & 15, gsl = ln >> 4;

  int abyte[4], bbyte[2];
#pragma unroll
  for (int i = 0; i < 4; ++i) {
    int ra = wm * 64 + i * 16 + arow;
    abyte[i] = ra * 64 + ((gsl ^ ((ra >> 1) & 3)) * 16);
  }
#pragma unroll
  for (int j = 0; j < 2; ++j) {
    int rb = wn * 32 + j * 16 + arow;
    bbyte[j] = rb * 64 + ((gsl ^ ((rb >> 1) & 3)) * 16);
  }

  const int srow = tid >> 2;
  const int sl = (tid & 3) ^ ((srow >> 1) & 3);
  const signed char* Ast = A + (bm + srow) * (size_t)K + sl * 16;
  const signed char* Bst = Bt + (bn + srow) * (size_t)K + sl * 16;

#define STG(T, dst) do { if ((T) < NT) { \
    size_t go = (size_t)(T) * 64; \
    gload_lds16(Ast + go, (dst) + wv * 1024); \
    gload_lds16(Ast + go + (size_t)64 * K, (dst) + 4096 + wv * 1024); \
    gload_lds16(Bst + go, (dst) + 8192 + wv * 1024); } } while (0)

  i32x4 acc[4][2];
#pragma unroll
  for (int i = 0; i < 4; ++i)
#pragma unroll
    for (int j = 0; j < 2; ++j) { acc[i][j][0] = 0; acc[i][j][1] = 0; acc[i][j][2] = 0; acc[i][j][3] = 0; }

  char* b0 = lds;
  char* b1 = lds + 12288;
  char* b2 = lds + 24576;

  STG(0, b0); STG(1, b1);
  VMW3();
  BARR();

#define ITER(T, bufR, bufS) do { \
    i32x4 af[4], bf[2]; \
    _Pragma("unroll") \
    for (int i = 0; i < 4; ++i) af[i] = *(const i32x4*)((bufR) + abyte[i]); \
    _Pragma("unroll") \
    for (int j = 0; j < 2; ++j) bf[j] = *(const i32x4*)((bufR) + 8192 + bbyte[j]); \
    STG((T) + 2, bufS); \
    __builtin_amdgcn_s_setprio(1); \
    _Pragma("unroll") \
    for (int i = 0; i < 4; ++i) \
      _Pragma("unroll") \
      for (int j = 0; j < 2; ++j) acc[i][j] = mfma16i8(af[i], bf[j], acc[i][j]); \
    __builtin_amdgcn_s_setprio(0); \
    if ((T) == NT - 2) { VMW0(); } else if ((T) < NT - 2) { VMW3(); } \
    BARR(); } while (0)

#pragma unroll 1
  for (int t = 0; t + 2 < NT; t += 3) {
    ITER(t, b0, b2);
    ITER(t + 1, b1, b0);
    ITER(t + 2, b2, b1);
  }
  ITER(NT - 2, b0, b2);
  ITER(NT - 1, b1, b0);
#undef ITER
#undef STG

#pragma unroll
  for (int i = 0; i < 4; ++i) {
    size_t rowb = bm + wm * 64 + i * 16 + gsl * 4;
#pragma unroll
    for (int j = 0; j < 2; ++j) {
      size_t col = bn + wn * 32 + j * 16 + arow;
      float s = sa * wsc[col];
#pragma unroll
      for (int r = 0; r < 4; ++r)
        C[(rowb + r) * E_DIM + col] = (float)acc[i][j][r] * s;
    }
  }
}

// ========= merged RoPE(q,k, table-driven, VECTORIZED) + V-transpose (f16) =========
// q/k path (z<2): 64 blocks x 32 rows. Each thread owns 8 contiguous dims
// (one short8 load + one short8 store); rotate-half partner (i <-> i+32) comes
// from lane tid^4 via 4x shfl_xor (lanes j and j^4 hold the two halves of the
// same row). 8x fewer memory instructions than the scalar-2B version.
__global__ void k_rvt(const unsigned short* __restrict__ qkv,
                      unsigned short* __restrict__ Qh, unsigned short* __restrict__ Kh,
                      unsigned short* __restrict__ Vt, const unsigned* __restrict__ sc,
                      const float2* __restrict__ trig) {
  __shared__ float tb[64][65];
  const int z = blockIdx.z;
  if (z < 2) {
    const unsigned short* x = qkv + (z ? 4194304 : 0);
    unsigned short* out = z ? Kh : Qh;
    float scale = fmaxf(__uint_as_float(sc[z]) * (1.f / 127.f), 1e-8f);
    float invs = 1.f / scale;
    const int h = blockIdx.y;
    const int tid = threadIdx.x;
    const int s = blockIdx.x * 32 + (tid >> 3);
    const int j = tid & 7;
    // my 8 raw values: dims [j*8, j*8+8)
    short8 v = *(const short8*)(x + (size_t)s * E_DIM + h * 64 + j * 8);
    // partner (dims +-32): lane tid^4 (same row: tid>>3 unchanged)
    int pi[4];
    {
      const int* vi = (const int*)&v;
#pragma unroll
      for (int w = 0; w < 4; ++w) pi[w] = __shfl_xor(vi[w], 4);
    }
    short8 p = *(const short8*)pi;
    // out[i]    = q0*cos_i - q1*sin_i   (j<4: mine=q0, partner=q1)
    // out[i+32] = q1*cos_i + q0*sin_i   (j>=4: mine=q1, partner=q0)
    const float sgn = (j < 4) ? -1.f : 1.f;
    const float2* tp = trig + s * 32 + (j & 3) * 8;
    short8 ro;
#pragma unroll
    for (int e = 0; e < 8; ++e) {
      float me = fq1(h2f((unsigned short)v[e]), invs, scale);
      float pe = fq1(h2f((unsigned short)p[e]), invs, scale);
      float2 t = tp[e];
      ro[e] = (short)f2h(me * t.x + sgn * (pe * t.y));
    }
    *(short8*)(out + (size_t)h * S_LEN * D_DIM + (size_t)s * D_DIM + j * 8) = ro;
    return;
  }
  if (blockIdx.x >= 32) return;
  const unsigned short* v = qkv + 2 * 4194304;
  float scale = fmaxf(__uint_as_float(sc[2]) * (1.f / 127.f), 1e-8f);
  float invs = 1.f / scale;
  int s0 = blockIdx.x * 64, h = blockIdx.y;
#pragma unroll
  for (int l = 0; l < 16; ++l) {
    int idx = threadIdx.x + l * 256;
    int r = idx >> 6, c = idx & 63;
    float x = h2f(v[(size_t)(s0 + r) * E_DIM + h * 64 + c]);
    tb[r][c] = fq1(x, invs, scale);
  }
  __syncthreads();
#pragma unroll
  for (int l = 0; l < 16; ++l) {
    int idx = threadIdx.x + l * 256;
    int d = idx >> 6, s = idx & 63;
    Vt[(size_t)h * D_DIM * S_LEN + (size_t)d * S_LEN + s0 + s] = f2h(tb[s][d]);
  }
}

// -------- causal flash attention: 128 q-rows/block (2 chunks), K/V shared --------
// R8 structure (measured best): 256 thr / 4 waves, each block owns TWO 64-row
// q-chunks; per K/V tile the kf/vf fragments are loaded ONCE and consumed by
// both chunks. Grid 512 = 32 heads x 16; balanced pairing so co-resident pairs
// sum nt = 34. launch_bounds (256,2) = 8 waves/CU.
// R10: + T13 defer-max (THR=8). When the wave-wide tile max <= m_old + 8, keep
// m_old: P = exp(S - m_old) <= e^8 (fits f16), skip the corr exp + 4 shfl
// broadcasts + 16-elem o-rescale on the serial chain. __all is wave-uniform ->
// uniform branch. First tile: m_old = -inf -> full path.
__global__ __launch_bounds__(256, 2)
void k_attn(const unsigned short* __restrict__ Qh, const unsigned short* __restrict__ Kh,
            const unsigned short* __restrict__ Vt, unsigned short* __restrict__ att,
            unsigned* __restrict__ amax) {
  __shared__ char Kbuf[2 * 8192];
  __shared__ char Vbuf[2 * 8192];
  __shared__ __align__(16) char Pb[8192];
  const int L = blockIdx.x;
  const int h = L & 31;
  const int g5 = L >> 5;                              // [0,16)
  const int qc = (g5 < 8) ? (15 - g5) : (g5 - 8);     // balanced pairing
  const int nt = 2 * qc + 2;
  const int tid = threadIdx.x;
  const int wv = tid >> 6, ln = tid & 63;
  const int arow = ln & 15, gsl = ln >> 4;
  const unsigned short* Qb = Qh + (size_t)h * S_LEN * D_DIM;
  const unsigned short* Kb = Kh + (size_t)h * S_LEN * D_DIM;
  const unsigned short* Vb = Vt + (size_t)h * D_DIM * S_LEN;
  const int qr0 = qc * 128 + wv * 16;                 // group 0 rows
  const int qr1 = qr0 + 64;                           // group 1 rows

  const int srow0 = tid >> 3, sch0 = (tid & 7) ^ (srow0 & 7);
  const int srow1 = 32 + (tid >> 3), sch1 = (tid & 7) ^ (srow1 & 7);

#define STAGEK(T, B) do { char* kd = Kbuf + (B) * 8192; const int tb_ = (T) * 64; \
    gload_lds16(Kb + (size_t)(tb_ + srow0) * D_DIM + sch0 * 8, kd + wv * 1024); \
    gload_lds16(Kb + (size_t)(tb_ + srow1) * D_DIM + sch1 * 8, kd + 4096 + wv * 1024); } while (0)
#define STAGEV(T, B) do { char* vd = Vbuf + (B) * 8192; const int tb_ = (T) * 64; \
    gload_lds16(Vb + (size_t)srow0 * S_LEN + tb_ + sch0 * 8, vd + wv * 1024); \
    gload_lds16(Vb + (size_t)srow1 * S_LEN + tb_ + sch1 * 8, vd + 4096 + wv * 1024); } while (0)

  short8 qa[2][2];
  qa[0][0] = *(const short8*)(Qb + (size_t)(qr0 + arow) * D_DIM + gsl * 8);
  qa[0][1] = *(const short8*)(Qb + (size_t)(qr0 + arow) * D_DIM + 32 + gsl * 8);
  qa[1][0] = *(const short8*)(Qb + (size_t)(qr1 + arow) * D_DIM + gsl * 8);
  qa[1][1] = *(const short8*)(Qb + (size_t)(qr1 + arow) * D_DIM + 32 + gsl * 8);

  f32x4 o[2][4];
  float mrow[2], lrow[2];
#pragma unroll
  for (int gq = 0; gq < 2; ++gq) {
    mrow[gq] = -INFINITY; lrow[gq] = 0.f;
#pragma unroll
    for (int d = 0; d < 4; ++d) { o[gq][d][0] = 0.f; o[gq][d][1] = 0.f; o[gq][d][2] = 0.f; o[gq][d][3] = 0.f; }
  }

  STAGEK(0, 0);
  STAGEV(0, 0);
  STAGEK(1, 1); STAGEV(1, 1);
  VMW4();
  BARR();

  char* Pw = Pb + wv * 2048 + arow * 128;
  const int arw7 = arow & 7;

#pragma unroll 1
  for (int t = 0; t < nt; ++t) {
    if (t >= 1 && t + 1 < nt) { STAGEK(t + 1, (t + 1) & 1); STAGEV(t + 1, (t + 1) & 1); }
    char* kb = Kbuf + (t & 1) * 8192;
    char* vb = Vbuf + (t & 1) * 8192;

    // shared K and V fragments: loaded once, consumed by both q-groups
    short8 kf[4][2];
#pragma unroll
    for (int kvb = 0; kvb < 4; ++kvb) {
      int row = kvb * 16 + arow;
      int sw = (row & 7) << 4;
      kf[kvb][0] = *(const short8*)(kb + row * 128 + ((gsl * 16) ^ sw));
      kf[kvb][1] = *(const short8*)(kb + row * 128 + ((64 + gsl * 16) ^ sw));
    }
    short8 vf[4][2];
#pragma unroll
    for (int d = 0; d < 4; ++d) {
      int row = d * 16 + arow;
      int sw = (row & 7) << 4;
      vf[d][0] = *(const short8*)(vb + row * 128 + ((gsl * 16) ^ sw));
      vf[d][1] = *(const short8*)(vb + row * 128 + ((64 + gsl * 16) ^ sw));
    }

    const int t0 = t * 64;

#pragma unroll
    for (int gq = 0; gq < 2; ++gq) {
      if (gq == 0 && t == nt - 1) continue;  // group 0 fully masked at last tile
      const int qrg = (gq == 0) ? qr0 : qr1;

      f32x4 s4[4];
#pragma unroll
      for (int kvb = 0; kvb < 4; ++kvb) {
        s4[kvb][0] = 0.f; s4[kvb][1] = 0.f; s4[kvb][2] = 0.f; s4[kvb][3] = 0.f;
      }
#pragma unroll
      for (int kvb = 0; kvb < 4; ++kvb) {
        s4[kvb] = mfma16h(kf[kvb][0], qa[gq][0], s4[kvb]);
        s4[kvb] = mfma16h(kf[kvb][1], qa[gq][1], s4[kvb]);
      }

      const int qrow = qrg + arow;
      if (t0 + 63 > qrow) {
#pragma unroll
        for (int kvb = 0; kvb < 4; ++kvb) {
          int colb = t0 + kvb * 16 + gsl * 4;
#pragma unroll
          for (int r = 0; r < 4; ++r)
            if (colb + r > qrow) s4[kvb][r] = -INFINITY;
        }
      }

      float smax = s4[0][0];
#pragma unroll
      for (int kvb = 0; kvb < 4; ++kvb)
#pragma unroll
        for (int r = 0; r < 4; ++r) smax = fmaxf(smax, s4[kvb][r]);
      smax = fmaxf(smax, __shfl_xor(smax, 16));
      smax = fmaxf(smax, __shfl_xor(smax, 32));

      // T13 defer-max: if no row's tile max exceeds m_old + 8, keep m_old and
      // skip the rescale chain (corr exp + 4 shfl + 16-mult o-rescale).
      float mn;
      if (__all(smax <= mrow[gq] + 8.f)) {
        mn = mrow[gq];
      } else {
        mn = fmaxf(mrow[gq], smax);
        float corr = __expf(mrow[gq] - mn);
        lrow[gq] *= corr;
        float corr_r[4];
#pragma unroll
        for (int r = 0; r < 4; ++r) corr_r[r] = __shfl(corr, gsl * 4 + r);
#pragma unroll
        for (int d = 0; d < 4; ++d)
#pragma unroll
          for (int r = 0; r < 4; ++r) o[gq][d][r] *= corr_r[r];
        mrow[gq] = mn;
      }

      float rs = 0.f;
      float p4[4][4];
#pragma unroll
      for (int kvb = 0; kvb < 4; ++kvb)
#pragma unroll
        for (int r = 0; r < 4; ++r) {
          p4[kvb][r] = __expf(s4[kvb][r] - mn);
          rs += p4[kvb][r];
        }
      rs += __shfl_xor(rs, 16);
      rs += __shfl_xor(rs, 32);
      lrow[gq] += rs;

      __builtin_amdgcn_wave_barrier();
#pragma unroll
      for (int kvb = 0; kvb < 4; ++kvb) {
        short4v pw;
        pw[0] = (short)f2h(p4[kvb][0]);
        pw[1] = (short)f2h(p4[kvb][1]);
        pw[2] = (short)f2h(p4[kvb][2]);
        pw[3] = (short)f2h(p4[kvb][3]);
        const int u = kvb * 2 + (gsl >> 1);
        *(short4v*)(Pw + ((u ^ arw7) << 4) + ((gsl & 1) << 3)) = pw;
      }
      __builtin_amdgcn_wave_barrier();
      short8 pa0 = *(const short8*)(Pw + ((gsl ^ arw7) << 4));
      short8 pa1 = *(const short8*)(Pw + (((4 + gsl) ^ arw7) << 4));
      __builtin_amdgcn_wave_barrier();

#pragma unroll
      for (int d = 0; d < 4; ++d) {
        o[gq][d] = mfma16h(pa0, vf[d][0], o[gq][d]);
        o[gq][d] = mfma16h(pa1, vf[d][1], o[gq][d]);
      }
    }

    VMW0();
    BARR();
  }
#undef STAGEK
#undef STAGEV

  float amx = 0.f;
#pragma unroll
  for (int gq = 0; gq < 2; ++gq) {
    const int qrg = (gq == 0) ? qr0 : qr1;
    float invl = 1.f / lrow[gq];
    float invl_r[4];
#pragma unroll
    for (int r = 0; r < 4; ++r) invl_r[r] = __shfl(invl, gsl * 4 + r);
#pragma unroll
    for (int r = 0; r < 4; ++r) {
      size_t row = (size_t)(qrg + gsl * 4 + r);
#pragma unroll
      for (int d = 0; d < 4; ++d) {
        float v = o[gq][d][r] * invl_r[r];
        att[row * E_DIM + h * 64 + d * 16 + arow] = f2h(v);
        amx = fmaxf(amx, fabsf(v));
      }
    }
  }

#pragma unroll
  for (int off = 32; off; off >>= 1) amx = fmaxf(amx, __shfl_xor(amx, off));
  if (ln == 0) atomicMax(amax + 3, __float_as_uint(amx));
}

// ---------------- act fake-quant f16 -> packed int8 (8 elems/thread) ----------------
__global__ void k_quant_act_i8(const unsigned short* __restrict__ in, uint2* __restrict__ out,
                               const unsigned* __restrict__ sc, int idx) {
  float scale = fmaxf(__uint_as_float(sc[idx]) * (1.f / 127.f), 1e-8f);
  float invs = 1.f / scale;
  int i = blockIdx.x * blockDim.x + threadIdx.x;
  short8 v = ((const short8*)in)[i];
  unsigned lo = 0, hi = 0;
#pragma unroll
  for (int e = 0; e < 4; ++e)
    lo |= (unsigned)(q8(h2f((unsigned short)v[e]), invs) & 255) << (8 * e);
#pragma unroll
  for (int e = 0; e < 4; ++e)
    hi |= (unsigned)(q8(h2f((unsigned short)v[4 + e]), invs) & 255) << (8 * e);
  uint2 pk; pk.x = lo; pk.y = hi;
  out[i] = pk;
}

extern "C" void kernel_launch(void* const* d_in, const int* in_sizes, int n_in,
                              void* d_out, int out_size, void* d_ws, size_t ws_size,
                              hipStream_t stream) {
  const float* hs = (const float*)d_in[0];
  const float* w_q = (const float*)d_in[1];
  const float* w_k = (const float*)d_in[2];
  const float* w_v = (const float*)d_in[3];
  const float* w_o = (const float*)d_in[4];

  char* ws = (char*)d_ws;
  unsigned short* wq_all = (unsigned short*)(ws);                 // 3 x E*E f16 (q,k,v)
  signed char* wo_i8 = (signed char*)(ws + 25165824);             // E*E i8
  float* wsc = (float*)(ws + 29360128);                           // 2048 f32
  float2* trig = (float2*)(ws + 30408704);                        // 65536 float2 (512KB)
  unsigned short* hsb = (unsigned short*)(ws + 33554432);         // S*E f16
  unsigned short* qkv16 = (unsigned short*)(ws + 41943040);       // 3 x S*E f16
  unsigned short* att = qkv16;                                    // alias q slab (f16)
  signed char* aq_i8 = (signed char*)(ws + 67108864);             // S*E i8
  unsigned short* Qh = (unsigned short*)(ws + 92274688);          // [H][S][D] f16
  unsigned short* Kh = (unsigned short*)(ws + 100663296);
  unsigned short* Vt = (unsigned short*)(ws + 109051904);         // [H][D][S] f16
  unsigned* sc = (unsigned*)(ws + 117440512);                     // absmax scalars

  k_prep<<<12545, 256, 0, stream>>>(hs, w_q, w_k, w_v, w_o, hsb, wq_all, wo_i8, wsc, sc, trig);
  k_gemm_qkv<<<dim3(192), 512, 0, stream>>>(hsb, wq_all, qkv16, sc, 0.125f);
  k_rvt<<<dim3(64, 32, 3), 256, 0, stream>>>(qkv16, Qh, Kh, Vt, sc, trig);
  k_attn<<<512, 256, 0, stream>>>(Qh, Kh, Vt, att, sc);
  k_quant_act_i8<<<2048, 256, 0, stream>>>(att, (uint2*)aq_i8, sc, 3);
  k_gemm_o<<<dim3(16, 32), 256, 0, stream>>>(aq_i8, wo_i8, (float*)d_out, sc, wsc);
}